// Round 2
// baseline (796.452 us; speedup 1.0000x reference)
//
#include <hip/hip_runtime.h>
#include <stdint.h>

// Problem constants (static per reference)
#define S_TOK   8192
#define MODEL_D 1024
#define N_EXP   64
#define CAP     128         // max(ceil(8192/64*1.0), 8)
#define SHIFT   4096        // int(S * 0.5)
#define SLAB    (N_EXP * CAP)           // 8192 floats per token in combine/dispatch
#define CDSIZE  ((size_t)S_TOK * SLAB)  // 67108864
#define OUT_FILL4 33554448              // (2+2*CDSIZE+64+... rounded down)/4 float4 zero-fill count

// d_out layout (float32): [l_aux(1) | combine(CDSIZE) | dispatch(CDSIZE) | exp_counts(64) | unrouted(1)]

// ws offsets (bytes, all 16B-aligned)
#define OFF_EXPERT   0          // int[8192]
#define OFF_GATE     32768      // float[8192]  gate value at argmax (=1/Z)
#define OFF_KEY      65536      // uint[8192]   sortable importance key
#define OFF_KEY2     98304      // uint[8192]   (expert<<13)|pos
#define OFF_MEPART   163840     // float[256][64] per-block gate column sums
#define OFF_HIST     229376     // int[256][64]   per-block argmax histograms
#define OFF_DROP     294912     // int[256]       per-block dropped-token counts
#define OFF_WGT      295936     // float[256][64][4] repacked gate weights: [d/4][e][d%4]

__device__ __forceinline__ unsigned f2key(float f) {
    // monotonic float->uint transform (ascending float == ascending uint)
    unsigned b = __float_as_uint(f);
    return (b & 0x80000000u) ? ~b : (b | 0x80000000u);
}

// K_fill: pure float4 zero-fill of out[0 .. 4*OUT_FILL4). Same pattern as
// rocclr fillBuffer (measured 6.29 TB/s). Indices 134217792/3 (exp_counts[63],
// unrouted) are outside the fill but written unconditionally by k_final.
__global__ __launch_bounds__(256) void k_fill(float4* __restrict__ out4) {
    const float4 z = make_float4(0.f, 0.f, 0.f, 0.f);
    size_t i = (size_t)blockIdx.x * 256 + threadIdx.x;
    const size_t stride = (size_t)gridDim.x * 256;
    for (; i < OUT_FILL4; i += stride) out4[i] = z;
}

// K0: repack wg [64][1024] -> wgT4 [256][64][4]: wgT4[d>>2][e][d&3] = wg[e][d].
// Lets the GEMM load 4 consecutive d's for its expert as ONE float4.
__global__ __launch_bounds__(256) void k0_repack(const float* __restrict__ wg,
                                                 float* __restrict__ wgT4) {
    int id0 = blockIdx.x * 256 + threadIdx.x;
#pragma unroll
    for (int i = 0; i < 4; ++i) {
        int id = id0 + i * 16384;            // 64*1024 = 65536 total
        int e = id >> 10;
        int d = id & 1023;
        wgT4[((d >> 2) * 64 + e) * 4 + (d & 3)] = wg[id];
    }
}

// K1: gate GEMM + softmax + argmax + importance key + per-block me/hist partials.
// 256 blocks x 256 threads; 32 tokens/block; wave handles 8 tokens, lane = expert.
// x staged through LDS in 32KB chunks with coalesced float4 loads (no reliance
// on scalar-load promotion of uniform addresses).
__global__ __launch_bounds__(256) void k1_gemm_softmax(
    const float* __restrict__ x, const float* __restrict__ wgT4,
    int* __restrict__ expert_id, float* __restrict__ gate1,
    unsigned* __restrict__ keys, float* __restrict__ me_part,
    int* __restrict__ hist_part)
{
    __shared__ float xs[32][256];    // 32KB x chunk tile
    __shared__ float lg[32][65];     // logits tile, padded (conflict-free columns)
    __shared__ float mrow[32], zrow[32];
    __shared__ int   exrow[32];
    __shared__ int   hist[64];
    __shared__ float mep[4][64];

    const int tid  = threadIdx.x;
    const int lane = tid & 63;       // expert index
    const int wv   = tid >> 6;
    const int tok0 = blockIdx.x * 32;

    const float4* xg  = (const float4*)x;
    const float4* wg4 = (const float4*)wgT4;

    float acc[8] = {0.f,0.f,0.f,0.f,0.f,0.f,0.f,0.f};

    for (int chunk = 0; chunk < 4; ++chunk) {
        __syncthreads();   // protect xs from previous chunk's readers
#pragma unroll
        for (int i = 0; i < 8; ++i) {
            int linear = tid + 256 * i;          // 0..2047
            int t  = linear >> 6;
            int c4 = linear & 63;
            ((float4*)xs)[t * 64 + c4] = xg[(size_t)(tok0 + t) * 256 + chunk * 64 + c4];
        }
        __syncthreads();

#pragma unroll 4
        for (int dd = 0; dd < 256; dd += 4) {
            int d = chunk * 256 + dd;
            float4 w = wg4[(d >> 2) * 64 + lane];    // 4 weights for (e=lane, d..d+3)
#pragma unroll
            for (int t = 0; t < 8; ++t) {
                float4 xv = *(const float4*)&xs[wv * 8 + t][dd];  // broadcast across lanes
                acc[t] = fmaf(xv.x, w.x, acc[t]);
                acc[t] = fmaf(xv.y, w.y, acc[t]);
                acc[t] = fmaf(xv.z, w.z, acc[t]);
                acc[t] = fmaf(xv.w, w.w, acc[t]);
            }
        }
    }
#pragma unroll
    for (int t = 0; t < 8; ++t) lg[wv * 8 + t][lane] = acc[t];
    __syncthreads();

    if (tid < 64) hist[tid] = 0;
    if (tid < 32) {
        const int t = tid;
        float m = lg[t][0]; int am = 0;
        for (int e = 1; e < 64; ++e) {
            float v = lg[t][e];
            if (v > m) { m = v; am = e; }   // strict > : first-occurrence argmax (jnp)
        }
        float z = 0.f;
        for (int e = 0; e < 64; ++e) z += expf(lg[t][e] - m);
        float rz = 1.0f / z;                // = max gate value
        mrow[t] = m; zrow[t] = rz; exrow[t] = am;
        int sG = tok0 + t;
        expert_id[sG] = am;
        gate1[sG] = rz;
        keys[sG] = f2key(-rz);              // importance = -maxgate, ascending key
    }
    __syncthreads();

    if (tid < 32) atomicAdd(&hist[exrow[tid]], 1);
    {   // me column partial sums: thread (e = tid&63, tg = tid>>6)
        const int e = tid & 63, tg = tid >> 6;
        float p = 0.f;
        for (int t = tg; t < 32; t += 4) p += expf(lg[t][e] - mrow[t]) * zrow[t];
        mep[tg][e] = p;
    }
    __syncthreads();

    if (tid < 64) {
        me_part[blockIdx.x * 64 + tid] = mep[0][tid] + mep[1][tid] + mep[2][tid] + mep[3][tid];
        hist_part[blockIdx.x * 64 + tid] = hist[tid];
    }
}

// K2: global rank by (importance key, index), pos = (rank+SHIFT)&(S-1),
// emit key2 = (expert<<13)|pos. O(S^2) counting scan with all keys in LDS.
// Scan index phase-swizzled by part so the 8 part-groups span all 32 banks.
__global__ __launch_bounds__(256) void k2_rank(const unsigned* __restrict__ keys,
                                               const int* __restrict__ expert_id,
                                               unsigned* __restrict__ key2)
{
    __shared__ uint4 k4[2048];   // all 8192 keys, 32 KB
    const int tid = threadIdx.x;
    const uint4* kg = (const uint4*)keys;
    for (int i = tid; i < 2048; i += 256) k4[i] = kg[i];
    __syncthreads();

    const int sl = tid >> 3, part = tid & 7;   // 32 tokens/block, 8 scan-threads/token
    const int sG = blockIdx.x * 32 + sl;
    const unsigned myk = ((const unsigned*)k4)[sG];
    int cnt = 0;
    const int qbase = part * 256;
    for (int q = 0; q < 256; ++q) {
        int qq = (q + part) & 255;             // bank-phase swizzle
        uint4 v = k4[qbase + qq];
        int j = (qbase + qq) * 4;
        cnt += (v.x < myk) || (v.x == myk && (j + 0) < sG);
        cnt += (v.y < myk) || (v.y == myk && (j + 1) < sG);
        cnt += (v.z < myk) || (v.z == myk && (j + 2) < sG);
        cnt += (v.w < myk) || (v.w == myk && (j + 3) < sG);
    }
    cnt += __shfl_down(cnt, 4);
    cnt += __shfl_down(cnt, 2);
    cnt += __shfl_down(cnt, 1);
    if (part == 0) {
        int pos = (cnt + SHIFT) & (S_TOK - 1);
        key2[sG] = ((unsigned)expert_id[sG] << 13) | (unsigned)pos;
    }
}

// K3: loc = rank within expert by pos; fused one-hot scatter into out
// (fill already zeroed it) + per-block dropped count.
__global__ __launch_bounds__(256) void k3_loc_scatter(const unsigned* __restrict__ key2,
                                                      const float* __restrict__ gate1,
                                                      float* __restrict__ out,
                                                      int* __restrict__ drop_part)
{
    __shared__ uint4 k4[2048];
    __shared__ int dropc;
    const int tid = threadIdx.x;
    if (tid == 0) dropc = 0;
    const uint4* kg = (const uint4*)key2;
    for (int i = tid; i < 2048; i += 256) k4[i] = kg[i];
    __syncthreads();

    const int sl = tid >> 3, part = tid & 7;
    const int sG = blockIdx.x * 32 + sl;
    const unsigned myk = ((const unsigned*)k4)[sG];
    const unsigned lo = myk & ~8191u;   // expert<<13
    int cnt = 0;
    const int qbase = part * 256;
    for (int q = 0; q < 256; ++q) {
        int qq = (q + part) & 255;
        uint4 v = k4[qbase + qq];
        cnt += (v.x >= lo) && (v.x < myk);
        cnt += (v.y >= lo) && (v.y < myk);
        cnt += (v.z >= lo) && (v.z < myk);
        cnt += (v.w >= lo) && (v.w < myk);
    }
    cnt += __shfl_down(cnt, 4);
    cnt += __shfl_down(cnt, 2);
    cnt += __shfl_down(cnt, 1);
    if (part == 0) {
        if (cnt >= CAP) {
            atomicAdd(&dropc, 1);
        } else {
            unsigned e = myk >> 13;
            size_t idx = 1 + (size_t)sG * SLAB + (size_t)e * CAP + (unsigned)cnt;
            out[idx] = gate1[sG];            // combine_weights one-hot
            out[idx + CDSIZE] = 1.0f;        // dispatch_mask one-hot
        }
    }
    __syncthreads();
    if (tid == 0) drop_part[blockIdx.x] = dropc;
}

// K_final: scalar outputs — l_aux, exp_counts, unrouted rate. One block.
__global__ __launch_bounds__(256) void k_final(const float* __restrict__ me_part,
                                               const int* __restrict__ hist_part,
                                               const int* __restrict__ drop_part,
                                               float* __restrict__ out)
{
    __shared__ float msum[4][64];
    __shared__ int   hsum[4][64];
    __shared__ float contrib[64];
    const int tid = threadIdx.x;
    const int e = tid & 63, qt = tid >> 6;
    float ms = 0.f; int hs = 0;
    for (int p = qt * 64; p < qt * 64 + 64; ++p) {
        ms += me_part[p * 64 + e];
        hs += hist_part[p * 64 + e];
    }
    msum[qt][e] = ms; hsum[qt][e] = hs;
    __syncthreads();
    if (tid < 64) {
        float m = msum[0][tid] + msum[1][tid] + msum[2][tid] + msum[3][tid];
        int   h = hsum[0][tid] + hsum[1][tid] + hsum[2][tid] + hsum[3][tid];
        out[1 + 2 * CDSIZE + tid] = (float)h;                               // exp_counts
        contrib[tid] = (m * (1.0f / S_TOK)) * ((float)h * (1.0f / S_TOK));
    }
    __syncthreads();
    if (tid == 0) {
        float sum = 0.f;
        for (int i = 0; i < 64; ++i) sum += contrib[i];
        out[0] = sum * (float)N_EXP * 0.01f;                                // l_aux
        int dr = 0;
        for (int p = 0; p < 256; ++p) dr += drop_part[p];
        out[1 + 2 * CDSIZE + 64] = (float)dr * (1.0f / S_TOK);              // unrouted
    }
}

extern "C" void kernel_launch(void* const* d_in, const int* in_sizes, int n_in,
                              void* d_out, int out_size, void* d_ws, size_t ws_size,
                              hipStream_t stream) {
    (void)in_sizes; (void)n_in; (void)out_size; (void)ws_size;
    const float* x  = (const float*)d_in[0];
    const float* wg = (const float*)d_in[1];
    float* out = (float*)d_out;
    char* ws = (char*)d_ws;

    int*      expert_id = (int*)(ws + OFF_EXPERT);
    float*    gate1     = (float*)(ws + OFF_GATE);
    unsigned* keys      = (unsigned*)(ws + OFF_KEY);
    unsigned* key2      = (unsigned*)(ws + OFF_KEY2);
    float*    me_part   = (float*)(ws + OFF_MEPART);
    int*      hist_part = (int*)(ws + OFF_HIST);
    int*      drop_part = (int*)(ws + OFF_DROP);
    float*    wgT4      = (float*)(ws + OFF_WGT);

    hipLaunchKernelGGL(k_fill,          dim3(8192), dim3(256), 0, stream, (float4*)out);
    hipLaunchKernelGGL(k0_repack,       dim3(64),   dim3(256), 0, stream, wg, wgT4);
    hipLaunchKernelGGL(k1_gemm_softmax, dim3(256),  dim3(256), 0, stream, x, wgT4,
                       expert_id, gate1, keys, me_part, hist_part);
    hipLaunchKernelGGL(k2_rank,         dim3(256),  dim3(256), 0, stream, keys, expert_id, key2);
    hipLaunchKernelGGL(k3_loc_scatter,  dim3(256),  dim3(256), 0, stream, key2, gate1, out, drop_part);
    hipLaunchKernelGGL(k_final,         dim3(1),    dim3(256), 0, stream,
                       me_part, hist_part, drop_part, out);
}

// Round 3
// 714.323 us; speedup vs baseline: 1.1150x; 1.1150x over previous
//
#include <hip/hip_runtime.h>
#include <stdint.h>

// Problem constants (static per reference)
#define S_TOK   8192
#define MODEL_D 1024
#define N_EXP   64
#define CAP     128         // max(ceil(8192/64*1.0), 8)
#define SHIFT   4096        // int(S * 0.5)
#define SLAB    (N_EXP * CAP)           // 8192 floats per token slab
#define CDSIZE  ((size_t)S_TOK * SLAB)  // 67108864
#define OUT_FILL4 33554448              // float4 count covering out[0..134217792)

#define GEMM_BLOCKS 512
#define TPB         16                  // tokens per gemm block

// d_out layout (float32): [l_aux(1) | combine(CDSIZE) | dispatch(CDSIZE) | exp_counts(64) | unrouted(1)]

// ws offsets (bytes)
#define OFF_EXPERT   0          // int[8192]
#define OFF_GATE     32768      // float[8192]   max-gate value (=1/Z)
#define OFF_KEY      65536      // uint[8192]    sortable importance key
#define OFF_KEY2     98304      // uint[8192]    (expert<<13)|pos
#define OFF_MEPART   131072     // float[512][64] per-block gate column sums
#define OFF_HIST     262144     // int[512][64]   per-block argmax histograms
#define OFF_WGT      393216     // float[256][64][4] repacked weights [d/4][e][d%4]

__device__ __forceinline__ unsigned f2key(float f) {
    // monotonic float->uint transform (ascending float == ascending uint)
    unsigned b = __float_as_uint(f);
    return (b & 0x80000000u) ? ~b : (b | 0x80000000u);
}

// N0: repack wg [64][1024] -> wgT4 [256][64][4] so gemm lanes (lane=expert)
// load 4 consecutive d's as ONE coalesced float4.
__global__ __launch_bounds__(256) void k0_repack(const float* __restrict__ wg,
                                                 float* __restrict__ wgT4) {
    int id0 = blockIdx.x * 256 + threadIdx.x;
#pragma unroll
    for (int i = 0; i < 4; ++i) {
        int id = id0 + i * 16384;            // 64*1024 total
        int e = id >> 10;
        int d = id & 1023;
        wgT4[((d >> 2) * 64 + e) * 4 + (d & 3)] = wg[id];
    }
}

// N1: fused zero-fill (blocks >= GEMM_BLOCKS) + gate GEMM/softmax/argmax/key +
// per-block me & histogram partials (blocks < GEMM_BLOCKS). The store-bound
// fill overlaps the VALU/LDS-bound gemm on the same CUs.
__global__ __launch_bounds__(256) void k1_fill_gemm(
    const float* __restrict__ x, const float* __restrict__ wgT4,
    float* __restrict__ out,
    int* __restrict__ expert_id, float* __restrict__ gate1,
    unsigned* __restrict__ keys, float* __restrict__ me_part,
    int* __restrict__ hist_part)
{
    const int b = blockIdx.x;
    if (b >= GEMM_BLOCKS) {
        // pure float4 zero-fill of out[0 .. 4*OUT_FILL4). The two trailing
        // scalars (exp_counts[63], unrouted) are written unconditionally in N2.
        const float4 z = make_float4(0.f, 0.f, 0.f, 0.f);
        float4* out4 = (float4*)out;
        size_t i = (size_t)(b - GEMM_BLOCKS) * 256 + threadIdx.x;
        for (; i < OUT_FILL4; i += (size_t)8192 * 256) out4[i] = z;
        return;
    }

    __shared__ float xs[TPB][256];   // 16 KB x chunk tile
    __shared__ float lg[TPB][65];    // logits tile, padded
    __shared__ float mrow[TPB], zrow[TPB];
    __shared__ int   exrow[TPB];
    __shared__ int   hist[64];
    __shared__ float mep[4][64];

    const int tid  = threadIdx.x;
    const int lane = tid & 63;       // expert index
    const int wv   = tid >> 6;
    const int tok0 = b * TPB;

    const float4* xg  = (const float4*)x;
    const float4* wg4 = (const float4*)wgT4;

    float acc[4] = {0.f, 0.f, 0.f, 0.f};

    for (int chunk = 0; chunk < 4; ++chunk) {
        __syncthreads();   // protect xs from previous chunk's readers
#pragma unroll
        for (int i = 0; i < 4; ++i) {
            int linear = tid + 256 * i;          // 0..1023
            int t  = linear >> 6;
            int c4 = linear & 63;
            ((float4*)xs)[t * 64 + c4] = xg[(size_t)(tok0 + t) * 256 + chunk * 64 + c4];
        }
        __syncthreads();

#pragma unroll 4
        for (int dd = 0; dd < 256; dd += 4) {
            int d = chunk * 256 + dd;
            float4 w = wg4[(d >> 2) * 64 + lane];    // coalesced: lanes consecutive
#pragma unroll
            for (int t = 0; t < 4; ++t) {
                float4 xv = *(const float4*)&xs[wv * 4 + t][dd];  // LDS broadcast
                acc[t] = fmaf(xv.x, w.x, acc[t]);
                acc[t] = fmaf(xv.y, w.y, acc[t]);
                acc[t] = fmaf(xv.z, w.z, acc[t]);
                acc[t] = fmaf(xv.w, w.w, acc[t]);
            }
        }
    }
#pragma unroll
    for (int t = 0; t < 4; ++t) lg[wv * 4 + t][lane] = acc[t];
    __syncthreads();

    if (tid < 64) hist[tid] = 0;
    if (tid < TPB) {
        const int t = tid;
        float m = lg[t][0]; int am = 0;
        for (int e = 1; e < 64; ++e) {
            float v = lg[t][e];
            if (v > m) { m = v; am = e; }   // strict > : first-occurrence argmax (jnp)
        }
        float z = 0.f;
        for (int e = 0; e < 64; ++e) z += expf(lg[t][e] - m);
        float rz = 1.0f / z;                // = max gate value
        mrow[t] = m; zrow[t] = rz; exrow[t] = am;
        int sG = tok0 + t;
        expert_id[sG] = am;
        gate1[sG] = rz;
        keys[sG] = f2key(-rz);              // importance = -maxgate, ascending
    }
    __syncthreads();

    if (tid < TPB) atomicAdd(&hist[exrow[tid]], 1);
    {   // me column partials: thread (e = tid&63, tg = tid>>6)
        const int e = tid & 63, tg = tid >> 6;
        float p = 0.f;
        for (int t = tg; t < TPB; t += 4) p += expf(lg[t][e] - mrow[t]) * zrow[t];
        mep[tg][e] = p;
    }
    __syncthreads();

    if (tid < 64) {
        me_part[b * 64 + tid] = mep[0][tid] + mep[1][tid] + mep[2][tid] + mep[3][tid];
        hist_part[b * 64 + tid] = hist[tid];
    }
}

// N2: blocks 0..255 — global rank by (importance key, index), pos=(rank+SHIFT)&8191,
// emit key2=(expert<<13)|pos (O(S^2) count, all keys in LDS, bank-phase swizzled).
// Block 256 — all scalar outputs: l_aux, exp_counts, unrouted.
// unrouted uses the identity: dropped = S - sum_e min(count_e, CAP)
// (per-expert ranks are a bijection 0..count_e-1, so drops are exactly the overflow).
__global__ __launch_bounds__(256) void k2_rank_scalars(
    const unsigned* __restrict__ keys, const int* __restrict__ expert_id,
    const float* __restrict__ me_part, const int* __restrict__ hist_part,
    unsigned* __restrict__ key2, float* __restrict__ out)
{
    const int tid = threadIdx.x;
    if (blockIdx.x == 256) {
        __shared__ float msum[4][64];
        __shared__ int   hsum[4][64];
        __shared__ float contrib[64];
        __shared__ int   keep[64];
        const int e = tid & 63, qt = tid >> 6;
        float ms = 0.f; int hs = 0;
        for (int p = qt * 128; p < qt * 128 + 128; ++p) {
            ms += me_part[p * 64 + e];
            hs += hist_part[p * 64 + e];
        }
        msum[qt][e] = ms; hsum[qt][e] = hs;
        __syncthreads();
        if (tid < 64) {
            float m = msum[0][tid] + msum[1][tid] + msum[2][tid] + msum[3][tid];
            int   h = hsum[0][tid] + hsum[1][tid] + hsum[2][tid] + hsum[3][tid];
            out[1 + 2 * CDSIZE + tid] = (float)h;                          // exp_counts
            contrib[tid] = (m * (1.0f / S_TOK)) * ((float)h * (1.0f / S_TOK));
            keep[tid] = (h < CAP) ? h : CAP;
        }
        __syncthreads();
        if (tid == 0) {
            float sum = 0.f; int kept = 0;
            for (int i = 0; i < 64; ++i) { sum += contrib[i]; kept += keep[i]; }
            out[0] = sum * (float)N_EXP * 0.01f;                           // l_aux
            out[1 + 2 * CDSIZE + 64] = (float)(S_TOK - kept) * (1.0f / S_TOK); // unrouted
        }
        return;
    }

    __shared__ uint4 k4[2048];   // all 8192 keys, 32 KB
    const uint4* kg = (const uint4*)keys;
    for (int i = tid; i < 2048; i += 256) k4[i] = kg[i];
    __syncthreads();

    const int sl = tid >> 3, part = tid & 7;   // 32 tokens/block, 8 scan-threads/token
    const int sG = blockIdx.x * 32 + sl;
    const unsigned myk = ((const unsigned*)k4)[sG];
    int cnt = 0;
    const int qbase = part * 256;
    for (int q = 0; q < 256; ++q) {
        int qq = (q + part) & 255;             // bank-phase swizzle (parts span banks)
        uint4 v = k4[qbase + qq];
        int j = (qbase + qq) * 4;
        cnt += (v.x < myk) || (v.x == myk && (j + 0) < sG);
        cnt += (v.y < myk) || (v.y == myk && (j + 1) < sG);
        cnt += (v.z < myk) || (v.z == myk && (j + 2) < sG);
        cnt += (v.w < myk) || (v.w == myk && (j + 3) < sG);
    }
    cnt += __shfl_down(cnt, 4);
    cnt += __shfl_down(cnt, 2);
    cnt += __shfl_down(cnt, 1);
    if (part == 0) {
        int pos = (cnt + SHIFT) & (S_TOK - 1);
        key2[sG] = ((unsigned)expert_id[sG] << 13) | (unsigned)pos;
    }
}

// N3: loc = within-expert rank by pos; one-hot scatter into the pre-zeroed out.
__global__ __launch_bounds__(256) void k3_loc_scatter(const unsigned* __restrict__ key2,
                                                      const float* __restrict__ gate1,
                                                      float* __restrict__ out)
{
    __shared__ uint4 k4[2048];
    const int tid = threadIdx.x;
    const uint4* kg = (const uint4*)key2;
    for (int i = tid; i < 2048; i += 256) k4[i] = kg[i];
    __syncthreads();

    const int sl = tid >> 3, part = tid & 7;
    const int sG = blockIdx.x * 32 + sl;
    const unsigned myk = ((const unsigned*)k4)[sG];
    const unsigned lo = myk & ~8191u;   // expert<<13
    int cnt = 0;
    const int qbase = part * 256;
    for (int q = 0; q < 256; ++q) {
        int qq = (q + part) & 255;
        uint4 v = k4[qbase + qq];
        cnt += (v.x >= lo) && (v.x < myk);
        cnt += (v.y >= lo) && (v.y < myk);
        cnt += (v.z >= lo) && (v.z < myk);
        cnt += (v.w >= lo) && (v.w < myk);
    }
    cnt += __shfl_down(cnt, 4);
    cnt += __shfl_down(cnt, 2);
    cnt += __shfl_down(cnt, 1);
    if (part == 0 && cnt < CAP) {
        unsigned e = myk >> 13;
        size_t idx = 1 + (size_t)sG * SLAB + (size_t)e * CAP + (unsigned)cnt;
        out[idx] = gate1[sG];            // combine_weights one-hot
        out[idx + CDSIZE] = 1.0f;        // dispatch_mask one-hot
    }
}

extern "C" void kernel_launch(void* const* d_in, const int* in_sizes, int n_in,
                              void* d_out, int out_size, void* d_ws, size_t ws_size,
                              hipStream_t stream) {
    (void)in_sizes; (void)n_in; (void)out_size; (void)ws_size;
    const float* x  = (const float*)d_in[0];
    const float* wg = (const float*)d_in[1];
    float* out = (float*)d_out;
    char* ws = (char*)d_ws;

    int*      expert_id = (int*)(ws + OFF_EXPERT);
    float*    gate1     = (float*)(ws + OFF_GATE);
    unsigned* keys      = (unsigned*)(ws + OFF_KEY);
    unsigned* key2      = (unsigned*)(ws + OFF_KEY2);
    float*    me_part   = (float*)(ws + OFF_MEPART);
    int*      hist_part = (int*)(ws + OFF_HIST);
    float*    wgT4      = (float*)(ws + OFF_WGT);

    hipLaunchKernelGGL(k0_repack,       dim3(64),                dim3(256), 0, stream, wg, wgT4);
    hipLaunchKernelGGL(k1_fill_gemm,    dim3(GEMM_BLOCKS + 8192), dim3(256), 0, stream,
                       x, wgT4, out, expert_id, gate1, keys, me_part, hist_part);
    hipLaunchKernelGGL(k2_rank_scalars, dim3(257),               dim3(256), 0, stream,
                       keys, expert_id, me_part, hist_part, key2, out);
    hipLaunchKernelGGL(k3_loc_scatter,  dim3(256),               dim3(256), 0, stream,
                       key2, gate1, out);
}